// Round 5
// baseline (126.068 us; speedup 1.0000x reference)
//
#include <hip/hip_runtime.h>
#include <math.h>

#define NPART 62
#define M 512
#define D 256
#define MARGIN 0.2f

typedef __attribute__((ext_vector_type(8))) _Float16 f16x8;
typedef __attribute__((ext_vector_type(2))) __fp16 fp16x2;
typedef __attribute__((ext_vector_type(4))) float f32x4;

// ws layout (bytes)
#define ACC_OFF 0                        // 62*4 floats (fsum, fcnt, mdsum)
#define X2_OFF  4096                     // 62*512 floats
#define HN_OFF  (4096 + 131072)          // 62*512 uint (float bits)
#define HPT_OFF (4096 + 2 * 131072)      // 62*512*16 floats (hpm sorted + suffix sums)

#define CSWAP(i, j) { const float lo_ = fminf(h[i], h[j]); const float hi_ = fmaxf(h[i], h[j]); h[i] = lo_; h[j] = hi_; }

// ---------- hp_prep: exact pos distances (sorted, +margin, suffix sums), x2, hn init ----------
// wave per 8-row label block; block = 4 waves.
__global__ __launch_bounds__(256, 4) void hp_prep(
    const float* __restrict__ feat, float* __restrict__ x2_ws,
    unsigned* __restrict__ hn_ws, float* __restrict__ hpT)
{
    __shared__ float X[4][8][260];   // +4 pad: spreads row banks
    __shared__ float hpbuf[4][64];

    const int t = threadIdx.x, lane = t & 63, w = t >> 6;
    const int gb = blockIdx.x * 4 + w;        // [0, 62*64)
    const int n = gb >> 6, lb = gb & 63;
    const int row0 = lb * 8;
    const float* F = feat + ((size_t)n * M + row0) * D;

    float sq[8];
#pragma unroll
    for (int rr = 0; rr < 8; ++rr) {
        const float4 v = *(const float4*)(F + rr * D + lane * 4);
        *(float4*)&X[w][rr][lane * 4] = v;
        sq[rr] = v.x * v.x + v.y * v.y + v.z * v.z + v.w * v.w;
    }
#pragma unroll
    for (int rr = 0; rr < 8; ++rr)
#pragma unroll
        for (int o = 32; o > 0; o >>= 1) sq[rr] += __shfl_xor(sq[rr], o);
    __syncthreads();

    const int a = lane >> 3, p = lane & 7;
    float s = 0.f;
#pragma unroll 4
    for (int kk = 0; kk < 64; ++kk) {
        const float4 xa = *(const float4*)&X[w][a][kk * 4];
        const float4 xp = *(const float4*)&X[w][p][kk * 4];
        const float d0 = xa.x - xp.x, d1 = xa.y - xp.y, d2_ = xa.z - xp.z, d3 = xa.w - xp.w;
        s += d0 * d0 + d1 * d1 + d2_ * d2_ + d3 * d3;
    }
    hpbuf[w][lane] = sqrtf(s);   // a==p -> exactly 0
    __syncthreads();

    if (lane < 8) {
        const int ar = row0 + lane;
        float h[8];
#pragma unroll
        for (int i = 0; i < 8; ++i) h[i] = hpbuf[w][lane * 8 + i] + MARGIN;
        // Batcher 19-CS sort, ascending
        CSWAP(0,1) CSWAP(2,3) CSWAP(4,5) CSWAP(6,7)
        CSWAP(0,2) CSWAP(1,3) CSWAP(4,6) CSWAP(5,7)
        CSWAP(1,2) CSWAP(5,6)
        CSWAP(0,4) CSWAP(1,5) CSWAP(2,6) CSWAP(3,7)
        CSWAP(2,4) CSWAP(3,5)
        CSWAP(1,2) CSWAP(3,4) CSWAP(5,6)
        float ss[8];
        ss[7] = h[7];
#pragma unroll
        for (int i = 6; i >= 0; --i) ss[i] = ss[i + 1] + h[i];
        float* dst = hpT + ((size_t)n * M + ar) * 16;
#pragma unroll
        for (int i = 0; i < 8; ++i) { dst[i] = h[i]; dst[8 + i] = ss[i]; }
        float myx2 = sq[0];
#pragma unroll
        for (int rr = 1; rr < 8; ++rr) myx2 = (lane == rr) ? sq[rr] : myx2;
        x2_ws[n * M + ar] = myx2;
        hn_ws[n * M + ar] = 0x7F800000u;   // +inf bits
    }
}

// ---------- main: fp16 MFMA gram over 128x128 tiles + fused loss epilogue ----------
__global__ __launch_bounds__(256, 4) void triplet_main(
    const float* __restrict__ feat, const int* __restrict__ label,
    const float* __restrict__ x2_ws, const float* __restrict__ hpT,
    unsigned* __restrict__ hn_ws, float* __restrict__ acc_ws)
{
    __shared__ __align__(16) _Float16 hS[256 * 32];   // 16 KB: rows 0-127 = A, 128-255 = B
    __shared__ float x2A[128], x2B[128];
    __shared__ int   labA[128], labB[128];
    __shared__ __align__(16) float hpTs[128 * 20];    // stride 20: bank spread + f4-aligned

    const int t    = threadIdx.x;
    const int lane = t & 63;
    const int w    = t >> 6;
    const int lr   = lane & 15;
    const int h    = lane >> 4;

    // bijective XCD swizzle: 992 = 8*124; part's 16 blocks share an XCD
    const int d_ = blockIdx.x;
    const int s  = (d_ & 7) * 124 + (d_ >> 3);
    const int n  = s >> 4;
    const int sub = s & 15;
    const int R0 = (sub >> 2) * 128;
    const int C0 = (sub & 3) * 128;
    const int rw = (w >> 1) * 64;
    const int cw = (w & 1) * 64;

    // block-local tables
    {
        const int i = t & 127;
        if (t < 128) {
            labA[i] = label[n * M + R0 + i];
            x2A[i]  = x2_ws[n * M + R0 + i];
        } else {
            labB[i] = label[n * M + C0 + i];
            x2B[i]  = x2_ws[n * M + C0 + i];
        }
        const int anchor = t >> 1, half = t & 1;
        const float* srcT = hpT + ((size_t)n * M + R0 + anchor) * 16 + half * 8;
        const float4 v0 = *(const float4*)srcT;
        const float4 v1 = *(const float4*)(srcT + 4);
        *(float4*)&hpTs[anchor * 20 + half * 8]     = v0;
        *(float4*)&hpTs[anchor * 20 + half * 8 + 4] = v1;
    }

    // staging: thread t owns LDS row t; global row R0+t (t<128) or C0+t-128
    const int grow = (t < 128) ? (R0 + t) : (C0 + t - 128);
    const float* srcRow = feat + ((size_t)n * M + grow) * D;
    const int swt = (t >> 1) & 3;

    // MFMA fragment offsets (halfs), swizzle slot = h ^ ((row>>1)&3)
    int aOff[4], bOff[4];
#pragma unroll
    for (int rb = 0; rb < 4; ++rb) {
        const int rowL = rw + rb * 16 + lr;
        aOff[rb] = rowL * 32 + ((h ^ ((rowL >> 1) & 3)) * 8);
    }
#pragma unroll
    for (int cb = 0; cb < 4; ++cb) {
        const int rowL = 128 + cw + cb * 16 + lr;
        bOff[cb] = rowL * 32 + ((h ^ ((rowL >> 1) & 3)) * 8);
    }

    f32x4 acc[4][4];
    const f32x4 zero4 = {0.f, 0.f, 0.f, 0.f};
#pragma unroll
    for (int i = 0; i < 4; ++i)
#pragma unroll
        for (int j = 0; j < 4; ++j) acc[i][j] = zero4;

    float4 L[8];
#pragma unroll
    for (int e = 0; e < 8; ++e) L[e] = *(const float4*)(srcRow + e * 4);

    for (int kc = 0; kc < 8; ++kc) {
        // convert current 32 floats -> 16 packed half2
        unsigned hw[16];
#pragma unroll
        for (int e = 0; e < 16; ++e) {
            const float4 vv = L[e >> 1];
            const float f0 = (e & 1) ? vv.z : vv.x;
            const float f1 = (e & 1) ? vv.w : vv.y;
            const fp16x2 hh = __builtin_amdgcn_cvt_pkrtz(f0, f1);
            hw[e] = __builtin_bit_cast(unsigned, hh);
        }
        __syncthreads();   // everyone done reading previous tile
#pragma unroll
        for (int g = 0; g < 4; ++g) {
            uint4 u; u.x = hw[g*4+0]; u.y = hw[g*4+1]; u.z = hw[g*4+2]; u.w = hw[g*4+3];
            *(uint4*)&hS[t * 32 + ((g ^ swt) * 8)] = u;
        }
        if (kc < 7) {
            const float* src2 = srcRow + (kc + 1) * 32;
#pragma unroll
            for (int e = 0; e < 8; ++e) L[e] = *(const float4*)(src2 + e * 4);
        }
        __syncthreads();   // tile visible

        f16x8 af[4];
#pragma unroll
        for (int rb = 0; rb < 4; ++rb) af[rb] = *(const f16x8*)&hS[aOff[rb]];
#pragma unroll
        for (int cb = 0; cb < 4; ++cb) {
            const f16x8 bf = *(const f16x8*)&hS[bOff[cb]];
#pragma unroll
            for (int rb = 0; rb < 4; ++rb)
                acc[rb][cb] = __builtin_amdgcn_mfma_f32_16x16x32_f16(af[rb], bf, acc[rb][cb], 0, 0, 0);
        }
    }

    // ---- epilogue ----
    float x2c[4]; int labc[4];
#pragma unroll
    for (int cb = 0; cb < 4; ++cb) {
        const int cl = cw + cb * 16 + lr;
        x2c[cb] = x2B[cl];
        labc[cb] = labB[cl];
    }

    float fsum = 0.f, mdsum = 0.f;
    int fcnt = 0;

#pragma unroll
    for (int rb = 0; rb < 4; ++rb) {
#pragma unroll
        for (int q = 0; q < 4; ++q) {
            const int rl   = rw + rb * 16 + h * 4 + q;
            const int labr = labA[rl];
            const float x2r = x2A[rl];
            const float4 hA = *(const float4*)&hpTs[rl * 20];       // hpm0..3 (sorted asc)
            const float4 hB = *(const float4*)&hpTs[rl * 20 + 4];   // hpm4..7
            float hn = 3.0e38f;
#pragma unroll
            for (int cb = 0; cb < 4; ++cb) {
                const float d2 = x2r + x2c[cb] - 2.f * acc[rb][cb][q];
                const float d  = (d2 > 0.f) ? sqrtf(d2) : 0.f;
                mdsum += d;
                const bool neg = (labc[cb] != labr);
                // 3-level binary search: j = count(hpm_i <= d), clamped to 7
                const bool c1 = (d >= hA.w);
                const float m1 = c1 ? hB.y : hA.y;
                const bool c2 = (d >= m1);
                const float mh = c2 ? hB.z : hB.x;
                const float ml = c2 ? hA.z : hA.x;
                const float m2 = c1 ? mh : ml;
                const bool c3 = (d >= m2);
                const int j = (c1 ? 4 : 0) + (c2 ? 2 : 0) + (c3 ? 1 : 0);
                const float SS = hpTs[rl * 20 + 8 + j];
                const int cnt = 8 - j;
                const float contrib = fmaf(-(float)cnt, d, SS);
                fsum += neg ? fmaxf(contrib, 0.f) : 0.f;
                fcnt += (neg && (contrib > 0.f)) ? cnt : 0;
                hn = neg ? fminf(hn, d) : hn;
            }
            hn = fminf(hn, __shfl_xor(hn, 1));
            hn = fminf(hn, __shfl_xor(hn, 2));
            hn = fminf(hn, __shfl_xor(hn, 4));
            hn = fminf(hn, __shfl_xor(hn, 8));
            if (lr == 0)
                atomicMin(&hn_ws[n * M + R0 + rl], __float_as_uint(hn));
        }
    }

    float fcf = (float)fcnt;
#pragma unroll
    for (int o = 32; o > 0; o >>= 1) {
        fsum  += __shfl_xor(fsum, o);
        fcf   += __shfl_xor(fcf, o);
        mdsum += __shfl_xor(mdsum, o);
    }
    if (lane == 0) {
        atomicAdd(&acc_ws[n * 4 + 0], fsum);
        atomicAdd(&acc_ws[n * 4 + 1], fcf);
        atomicAdd(&acc_ws[n * 4 + 2], mdsum);
    }
}

// ---------- finalize: hard loss from hn table + hp max, write outputs ----------
__global__ __launch_bounds__(512) void triplet_finalize(
    const float* __restrict__ acc_ws, const unsigned* __restrict__ hn_ws,
    const float* __restrict__ hpT, float* __restrict__ out)
{
    __shared__ float red[8];
    const int n = blockIdx.x, t = threadIdx.x, lane = t & 63, w = t >> 6;
    const float hn   = __uint_as_float(hn_ws[n * M + t]);
    const float hpm7 = hpT[((size_t)n * M + t) * 16 + 7];   // max(hp)+margin
    float hd = fmaxf(hpm7 - hn, 0.f);
#pragma unroll
    for (int o = 32; o > 0; o >>= 1) hd += __shfl_xor(hd, o);
    if (lane == 0) red[w] = hd;
    __syncthreads();
    if (t == 0) {
        float hsum = 0.f;
#pragma unroll
        for (int i = 0; i < 8; ++i) hsum += red[i];
        const float fs = acc_ws[n * 4 + 0];
        const float fc = acc_ws[n * 4 + 1];
        const float md = acc_ws[n * 4 + 2];
        out[n]             = (fc == 0.f) ? 0.f : fs / fmaxf(fc, 1.f);
        out[NPART + n]     = hsum / (float)M;
        out[2 * NPART + n] = md / ((float)M * (float)M);
        out[3 * NPART + n] = fc;
    }
}

extern "C" void kernel_launch(void* const* d_in, const int* in_sizes, int n_in,
                              void* d_out, int out_size, void* d_ws, size_t ws_size,
                              hipStream_t stream)
{
    (void)in_sizes; (void)n_in; (void)out_size; (void)ws_size;
    const float* feat  = (const float*)d_in[0];
    const int*   label = (const int*)d_in[1];

    float*    acc_ws = (float*)((char*)d_ws + ACC_OFF);
    float*    x2_ws  = (float*)((char*)d_ws + X2_OFF);
    unsigned* hn_ws  = (unsigned*)((char*)d_ws + HN_OFF);
    float*    hpT    = (float*)((char*)d_ws + HPT_OFF);

    (void)hipMemsetAsync(acc_ws, 0, NPART * 4 * sizeof(float), stream);
    hp_prep<<<dim3(NPART * 64 / 4), 256, 0, stream>>>(feat, x2_ws, hn_ws, hpT);
    triplet_main<<<dim3(992), 256, 0, stream>>>(feat, label, x2_ws, hpT, hn_ws, acc_ws);
    triplet_finalize<<<dim3(NPART), 512, 0, stream>>>(acc_ws, hn_ws, hpT, (float*)d_out);
}

// Round 6
// 93.055 us; speedup vs baseline: 1.3548x; 1.3548x over previous
//
#include <hip/hip_runtime.h>
#include <math.h>

#define NPART 62
#define M 512
#define D 256
#define MARGIN 0.2f

typedef __attribute__((ext_vector_type(8))) _Float16 f16x8;
typedef __attribute__((ext_vector_type(2))) __fp16 fp16x2;
typedef __attribute__((ext_vector_type(4))) float f32x4;

// ws layout (bytes)
#define ACC_OFF   0                         // 62*4 floats (fsum, fcnt, mdsum)
#define X2_OFF    4096                      // 62*512 floats
#define HN_OFF    (4096 + 131072)           // 62*512 uint (float bits)
#define HPT_OFF   (4096 + 2 * 131072)       // 62*512*16 floats
#define PLANE_OFF (HPT_OFF + 2031616)       // 62*512*256 halfs (16.25 MB), pre-swizzled

#define CSWAP(i, j) { const float lo_ = fminf(h[i], h[j]); const float hi_ = fmaxf(h[i], h[j]); h[i] = lo_; h[j] = hi_; }

// ---------- hp_prep: exact pos distances (sorted,+margin,suffix sums), x2, hn init,
// ----------          and fp16 plane (RTZ, group-swizzle baked into global layout)
__global__ __launch_bounds__(256, 4) void hp_prep(
    const float* __restrict__ feat, float* __restrict__ x2_ws,
    unsigned* __restrict__ hn_ws, float* __restrict__ hpT,
    unsigned short* __restrict__ plane)
{
    __shared__ float X[4][8][260];   // +4 pad
    __shared__ float hpbuf[4][64];

    const int t = threadIdx.x, lane = t & 63, w = t >> 6;
    const int gb = blockIdx.x * 4 + w;        // [0, 62*64)
    const int n = gb >> 6, lb = gb & 63;
    const int row0 = lb * 8;
    const float* F = feat + ((size_t)n * M + row0) * D;

    float sq[8];
#pragma unroll
    for (int rr = 0; rr < 8; ++rr) {
        const float4 v = *(const float4*)(F + rr * D + lane * 4);
        *(float4*)&X[w][rr][lane * 4] = v;
        sq[rr] = v.x * v.x + v.y * v.y + v.z * v.z + v.w * v.w;
        // fp16 convert + store to pre-swizzled plane
        const fp16x2 h01 = __builtin_amdgcn_cvt_pkrtz(v.x, v.y);
        const fp16x2 h23 = __builtin_amdgcn_cvt_pkrtz(v.z, v.w);
        uint2 u;
        u.x = __builtin_bit_cast(unsigned, h01);
        u.y = __builtin_bit_cast(unsigned, h23);
        const int row = row0 + rr;
        const int sw = (row >> 1) & 3;
        const size_t off = ((size_t)n * M + row) * D +
                           (lane >> 3) * 32 + ((((lane >> 1) & 3) ^ sw) * 8) + (lane & 1) * 4;
        *(uint2*)(plane + off) = u;
    }
#pragma unroll
    for (int rr = 0; rr < 8; ++rr)
#pragma unroll
        for (int o = 32; o > 0; o >>= 1) sq[rr] += __shfl_xor(sq[rr], o);
    __syncthreads();

    const int a = lane >> 3, p = lane & 7;
    float s = 0.f;
#pragma unroll 4
    for (int kk = 0; kk < 64; ++kk) {
        const float4 xa = *(const float4*)&X[w][a][kk * 4];
        const float4 xp = *(const float4*)&X[w][p][kk * 4];
        const float d0 = xa.x - xp.x, d1 = xa.y - xp.y, d2_ = xa.z - xp.z, d3 = xa.w - xp.w;
        s += d0 * d0 + d1 * d1 + d2_ * d2_ + d3 * d3;
    }
    hpbuf[w][lane] = sqrtf(s);
    __syncthreads();

    if (lane < 8) {
        const int ar = row0 + lane;
        float h[8];
#pragma unroll
        for (int i = 0; i < 8; ++i) h[i] = hpbuf[w][lane * 8 + i] + MARGIN;
        CSWAP(0,1) CSWAP(2,3) CSWAP(4,5) CSWAP(6,7)
        CSWAP(0,2) CSWAP(1,3) CSWAP(4,6) CSWAP(5,7)
        CSWAP(1,2) CSWAP(5,6)
        CSWAP(0,4) CSWAP(1,5) CSWAP(2,6) CSWAP(3,7)
        CSWAP(2,4) CSWAP(3,5)
        CSWAP(1,2) CSWAP(3,4) CSWAP(5,6)
        float ss[8];
        ss[7] = h[7];
#pragma unroll
        for (int i = 6; i >= 0; --i) ss[i] = ss[i + 1] + h[i];
        float* dst = hpT + ((size_t)n * M + ar) * 16;
#pragma unroll
        for (int i = 0; i < 8; ++i) { dst[i] = h[i]; dst[8 + i] = ss[i]; }
        float myx2 = sq[0];
#pragma unroll
        for (int rr = 1; rr < 8; ++rr) myx2 = (lane == rr) ? sq[rr] : myx2;
        x2_ws[n * M + ar] = myx2;
        hn_ws[n * M + ar] = 0x7F800000u;
    }
}

// ---------- main: fp16 MFMA gram over 128x128 tiles, dbuf LDS, fused loss ----------
__global__ __launch_bounds__(256, 3) void triplet_main(
    const unsigned short* __restrict__ plane,
    const float* __restrict__ x2_ws, const float* __restrict__ hpT,
    unsigned* __restrict__ hn_ws, float* __restrict__ acc_ws)
{
    __shared__ __align__(16) unsigned short hS[2][256 * 32];   // 2 x 16 KB
    __shared__ float x2A[128], x2B[128];
    __shared__ __align__(16) float hpTs[128 * 20];

    const int t    = threadIdx.x;
    const int lane = t & 63;
    const int w    = t >> 6;
    const int lr   = lane & 15;
    const int h    = lane >> 4;

    // bijective XCD swizzle: 992 = 8*124; part's 16 blocks share an XCD
    const int d_ = blockIdx.x;
    const int s  = (d_ & 7) * 124 + (d_ >> 3);
    const int n  = s >> 4;
    const int sub = s & 15;
    const int R0 = (sub >> 2) * 128;
    const int C0 = (sub & 3) * 128;
    const int rw = (w >> 1) * 64;
    const int cw = (w & 1) * 64;

    if (t < 128) x2A[t] = x2_ws[n * M + R0 + t];
    else         x2B[t - 128] = x2_ws[n * M + C0 + t - 128];
    {
        const int anchor = t >> 1, half = t & 1;
        const float* srcT = hpT + ((size_t)n * M + R0 + anchor) * 16 + half * 8;
        const float4 v0 = *(const float4*)srcT;
        const float4 v1 = *(const float4*)(srcT + 4);
        *(float4*)&hpTs[anchor * 20 + half * 8]     = v0;
        *(float4*)&hpTs[anchor * 20 + half * 8 + 4] = v1;
    }

    // coalesced staging: chunk idx = t + 256*i -> rowLocal = idx>>2, group slot = idx&3
    const unsigned short* pb = plane + (size_t)n * M * D;
    const unsigned short* src[4];
    int dstH[4];
#pragma unroll
    for (int i = 0; i < 4; ++i) {
        const int idx = t + 256 * i;
        const int rowLocal = idx >> 2, gg = idx & 3;
        const int grow = (rowLocal < 128) ? (R0 + rowLocal) : (C0 + rowLocal - 128);
        src[i]  = pb + (size_t)grow * D + gg * 8;
        dstH[i] = idx * 8;
    }

    // fragment offsets (halfs): slot = h ^ ((rowL>>1)&3); true k-order guaranteed
    int aOff[4], bOff[4];
#pragma unroll
    for (int rb = 0; rb < 4; ++rb) {
        const int rowL = rw + rb * 16 + lr;
        aOff[rb] = rowL * 32 + ((h ^ ((rowL >> 1) & 3)) * 8);
    }
#pragma unroll
    for (int cb = 0; cb < 4; ++cb) {
        const int rowL = 128 + cw + cb * 16 + lr;
        bOff[cb] = rowL * 32 + ((h ^ ((rowL >> 1) & 3)) * 8);
    }

    f32x4 acc[4][4];
    const f32x4 zero4 = {0.f, 0.f, 0.f, 0.f};
#pragma unroll
    for (int i = 0; i < 4; ++i)
#pragma unroll
        for (int j = 0; j < 4; ++j) acc[i][j] = zero4;

    uint4 L[4];
#pragma unroll
    for (int i = 0; i < 4; ++i) L[i] = *(const uint4*)(src[i]);
#pragma unroll
    for (int i = 0; i < 4; ++i) *(uint4*)&hS[0][dstH[i]] = L[i];
    __syncthreads();

    for (int kc = 0; kc < 8; ++kc) {
        if (kc < 7) {
#pragma unroll
            for (int i = 0; i < 4; ++i)
                L[i] = *(const uint4*)(src[i] + (kc + 1) * 32);
        }
        const unsigned short* buf = hS[kc & 1];
        f16x8 af[4];
#pragma unroll
        for (int rb = 0; rb < 4; ++rb) af[rb] = *(const f16x8*)&buf[aOff[rb]];
#pragma unroll
        for (int cb = 0; cb < 4; ++cb) {
            const f16x8 bf = *(const f16x8*)&buf[bOff[cb]];
#pragma unroll
            for (int rb = 0; rb < 4; ++rb)
                acc[rb][cb] = __builtin_amdgcn_mfma_f32_16x16x32_f16(af[rb], bf, acc[rb][cb], 0, 0, 0);
        }
        if (kc < 7) {
            unsigned short* nbuf = hS[(kc + 1) & 1];
#pragma unroll
            for (int i = 0; i < 4; ++i) *(uint4*)&nbuf[dstH[i]] = L[i];
        }
        __syncthreads();
    }

    // ---- epilogue ----
    float x2c[4]; int labc[4];
#pragma unroll
    for (int cb = 0; cb < 4; ++cb) {
        const int cl = cw + cb * 16 + lr;
        x2c[cb] = x2B[cl];
        labc[cb] = (C0 + cl) >> 3;     // labels are 8-blocks of the row index
    }

    float fsum = 0.f, mdsum = 0.f;
    int fcnt = 0;

#pragma unroll
    for (int rb = 0; rb < 4; ++rb) {
#pragma unroll
        for (int q = 0; q < 4; ++q) {
            const int rl   = rw + rb * 16 + h * 4 + q;
            const int labr = (R0 + rl) >> 3;
            const float x2r = x2A[rl];
            const float4 hA = *(const float4*)&hpTs[rl * 20];
            const float4 hB = *(const float4*)&hpTs[rl * 20 + 4];
            float hn = 3.0e38f;
#pragma unroll
            for (int cb = 0; cb < 4; ++cb) {
                const float d2 = x2r + x2c[cb] - 2.f * acc[rb][cb][q];
                const float d  = (d2 > 0.f) ? sqrtf(d2) : 0.f;
                mdsum += d;
                const bool neg = (labc[cb] != labr);
                const bool c1 = (d >= hA.w);
                const float m1 = c1 ? hB.y : hA.y;
                const bool c2 = (d >= m1);
                const float mh = c2 ? hB.z : hB.x;
                const float ml = c2 ? hA.z : hA.x;
                const float m2 = c1 ? mh : ml;
                const bool c3 = (d >= m2);
                const int j = (c1 ? 4 : 0) + (c2 ? 2 : 0) + (c3 ? 1 : 0);
                const float SS = hpTs[rl * 20 + 8 + j];
                const int cnt = 8 - j;
                const float contrib = fmaf(-(float)cnt, d, SS);
                fsum += neg ? fmaxf(contrib, 0.f) : 0.f;
                fcnt += (neg && (contrib > 0.f)) ? cnt : 0;
                hn = neg ? fminf(hn, d) : hn;
            }
            hn = fminf(hn, __shfl_xor(hn, 1));
            hn = fminf(hn, __shfl_xor(hn, 2));
            hn = fminf(hn, __shfl_xor(hn, 4));
            hn = fminf(hn, __shfl_xor(hn, 8));
            if (lr == 0)
                atomicMin(&hn_ws[n * M + R0 + rl], __float_as_uint(hn));
        }
    }

    float fcf = (float)fcnt;
#pragma unroll
    for (int o = 32; o > 0; o >>= 1) {
        fsum  += __shfl_xor(fsum, o);
        fcf   += __shfl_xor(fcf, o);
        mdsum += __shfl_xor(mdsum, o);
    }
    if (lane == 0) {
        atomicAdd(&acc_ws[n * 4 + 0], fsum);
        atomicAdd(&acc_ws[n * 4 + 1], fcf);
        atomicAdd(&acc_ws[n * 4 + 2], mdsum);
    }
}

// ---------- finalize ----------
__global__ __launch_bounds__(512) void triplet_finalize(
    const float* __restrict__ acc_ws, const unsigned* __restrict__ hn_ws,
    const float* __restrict__ hpT, float* __restrict__ out)
{
    __shared__ float red[8];
    const int n = blockIdx.x, t = threadIdx.x, lane = t & 63, w = t >> 6;
    const float hn   = __uint_as_float(hn_ws[n * M + t]);
    const float hpm7 = hpT[((size_t)n * M + t) * 16 + 7];
    float hd = fmaxf(hpm7 - hn, 0.f);
#pragma unroll
    for (int o = 32; o > 0; o >>= 1) hd += __shfl_xor(hd, o);
    if (lane == 0) red[w] = hd;
    __syncthreads();
    if (t == 0) {
        float hsum = 0.f;
#pragma unroll
        for (int i = 0; i < 8; ++i) hsum += red[i];
        const float fs = acc_ws[n * 4 + 0];
        const float fc = acc_ws[n * 4 + 1];
        const float md = acc_ws[n * 4 + 2];
        out[n]             = (fc == 0.f) ? 0.f : fs / fmaxf(fc, 1.f);
        out[NPART + n]     = hsum / (float)M;
        out[2 * NPART + n] = md / ((float)M * (float)M);
        out[3 * NPART + n] = fc;
    }
}

extern "C" void kernel_launch(void* const* d_in, const int* in_sizes, int n_in,
                              void* d_out, int out_size, void* d_ws, size_t ws_size,
                              hipStream_t stream)
{
    (void)in_sizes; (void)n_in; (void)out_size; (void)ws_size;
    const float* feat  = (const float*)d_in[0];

    float*          acc_ws = (float*)((char*)d_ws + ACC_OFF);
    float*          x2_ws  = (float*)((char*)d_ws + X2_OFF);
    unsigned*       hn_ws  = (unsigned*)((char*)d_ws + HN_OFF);
    float*          hpT    = (float*)((char*)d_ws + HPT_OFF);
    unsigned short* plane  = (unsigned short*)((char*)d_ws + PLANE_OFF);

    (void)hipMemsetAsync(acc_ws, 0, NPART * 4 * sizeof(float), stream);
    hp_prep<<<dim3(NPART * 64 / 4), 256, 0, stream>>>(feat, x2_ws, hn_ws, hpT, plane);
    triplet_main<<<dim3(992), 256, 0, stream>>>(plane, x2_ws, hpT, hn_ws, acc_ws);
    triplet_finalize<<<dim3(NPART), 512, 0, stream>>>(acc_ws, hn_ws, hpT, (float*)d_out);
}